// Round 15
// baseline (642.641 us; speedup 1.0000x reference)
//
#include <hip/hip_runtime.h>

typedef short bf16x8 __attribute__((ext_vector_type(8)));
typedef float f32x4 __attribute__((ext_vector_type(4)));
typedef unsigned short u16;
typedef u16 u16x4 __attribute__((ext_vector_type(4)));
typedef u16 u16x8 __attribute__((ext_vector_type(8)));

__device__ __forceinline__ float bf2f(u16 u) {
  union { float f; unsigned int i; } x; x.i = ((unsigned int)u) << 16; return x.f;
}
__device__ __forceinline__ u16 f2bf(float f) {
  union { float f; unsigned int i; } x; x.f = f;
  unsigned int r = x.i + 0x7fffu + ((x.i >> 16) & 1u);
  return (u16)(r >> 16);
}
__device__ __forceinline__ void st_out_(void* out, size_t idx, float v, int f32) {
  if (f32) ((float*)out)[idx] = v;
  else ((u16*)out)[idx] = f2bf(v);
}

// ---------------- dtype detection: fp32 vs bf16 device buffers ----------------
__global__ void k_detect(const u16* __restrict__ xx, int* flag) {
  int j = threadIdx.x;
  u16 u = xx[2 * j];
  int ex = (u >> 7) & 0xFF;
  int insane = (u != 0) && (ex < 100 || ex > 140);
  unsigned long long m = __ballot(insane);
  if (j == 0) flag[0] = (__popcll(m) > 8) ? 1 : 0;   // 1 = fp32
}

// ---------------- input normalization to bf16 (4 elems/thread) ----------------
__global__ void k_cvt_big(const void* __restrict__ src, u16* __restrict__ dst, int n4,
                          const int* __restrict__ flag) {
  int i = blockIdx.x * 256 + threadIdx.x;
  if (i >= n4) return;
  if (*flag) {
    float4 v = reinterpret_cast<const float4*>(src)[i];
    u16x4 o;
    o[0] = f2bf(v.x); o[1] = f2bf(v.y); o[2] = f2bf(v.z); o[3] = f2bf(v.w);
    reinterpret_cast<u16x4*>(dst)[i] = o;
  } else {
    reinterpret_cast<u16x4*>(dst)[i] = reinterpret_cast<const u16x4*>(src)[i];
  }
}

#define NSEG 38
struct Cvt { const void* src[NSEG]; int off[NSEG + 1]; };
__global__ void k_cvt_all(Cvt c, u16* __restrict__ dst, int total, const int* __restrict__ flag) {
  int i = blockIdx.x * 256 + threadIdx.x;
  if (i >= total) return;
  int s = 0;
  #pragma unroll 1
  while (i >= c.off[s + 1]) s++;
  int j = i - c.off[s];
  dst[i] = (*flag) ? f2bf(((const float*)c.src[s])[j]) : ((const u16*)c.src[s])[j];
}

// zero-padded colbias for fused res+layer0 GEMM: [0 x256 | rb0 x256]
__global__ void k_padbias(const u16* __restrict__ rb, u16* cbz) {
  int i = blockIdx.x * 256 + threadIdx.x;
  if (i < 512) cbz[i] = (i < 256) ? (u16)0 : rb[i - 256];
}
// concat two 256-vectors
__global__ void k_cat2(const u16* __restrict__ a, const u16* __restrict__ b, u16* dst) {
  int i = blockIdx.x * 256 + threadIdx.x;
  if (i < 512) dst[i] = (i < 256) ? a[i] : b[i - 256];
}
// gather rows: out[b] = h[idx[b]]
__global__ void k_gather(const u16* __restrict__ h, const int* __restrict__ idx,
                         u16* __restrict__ out, int rows) {
  int b = blockIdx.x, t = threadIdx.x;
  if (b < rows) out[(size_t)b * 256 + t] = h[(size_t)idx[b] * 256 + t];
}

// ---------------- fused weight transpose: dst[s][n*K+k] = src[s][k*NC+n] ----------------
#define NTR 10
struct Tr { const u16* src[NTR]; u16* dst[NTR]; int lk[NTR]; int nc[NTR]; int off[NTR + 1]; };
__global__ void k_tr_all(Tr c, int total) {
  int i = blockIdx.x * 256 + threadIdx.x;
  if (i >= total) return;
  int s = 0;
  #pragma unroll 1
  while (i >= c.off[s + 1]) s++;
  int j = i - c.off[s];
  int K = 1 << c.lk[s];
  int nrow = j >> c.lk[s], k = j & (K - 1);
  c.dst[s][j] = c.src[s][k * c.nc[s] + nrow];
}

// ---------------- graph preprocessing ----------------
__global__ void k_init(int* deg, int* cursor, int n) {
  int i = blockIdx.x * 256 + threadIdx.x;
  if (i < n) { deg[i] = 1; cursor[i] = 0; }
}
__global__ void k_deg(const int* __restrict__ dst, int* deg, int e) {
  int i = blockIdx.x * 256 + threadIdx.x;
  if (i < e) atomicAdd(&deg[dst[i]], 1);
}
__global__ void k_dinv(const int* __restrict__ deg, float* dinv, int n) {
  int i = blockIdx.x * 256 + threadIdx.x;
  if (i < n) dinv[i] = rsqrtf((float)deg[i]);
}
#define SCB 4096
__global__ __launch_bounds__(256) void k_scanA(const int* __restrict__ deg, int* bsum, int n) {
  int b = blockIdx.x, t = threadIdx.x;
  int base = b * SCB;
  int s = 0;
  for (int j = t; j < SCB; j += 256) { int i = base + j; s += (i < n) ? deg[i] - 1 : 0; }
  int l = t & 63, wid = t >> 6;
  #pragma unroll
  for (int o = 32; o; o >>= 1) s += __shfl_xor(s, o);
  __shared__ int red[4];
  if (l == 0) red[wid] = s;
  __syncthreads();
  if (t == 0) bsum[b] = red[0] + red[1] + red[2] + red[3];
}
__global__ void k_scanB(int* bsum, int nb, int* off, int n) {
  if (threadIdx.x == 0) {
    int c = 0;
    for (int i = 0; i < nb; i++) { int v = bsum[i]; bsum[i] = c; c += v; }
    off[n] = c;
  }
}
__global__ __launch_bounds__(256) void k_scanC(const int* __restrict__ deg, const int* __restrict__ bsum,
                                               int* off, int n) {
  int b = blockIdx.x, t = threadIdx.x;
  int base = b * SCB + t * 16;
  int loc[16]; int s = 0;
  #pragma unroll
  for (int j = 0; j < 16; j++) { int i = base + j; loc[j] = s; s += (i < n) ? deg[i] - 1 : 0; }
  int l = t & 63, wid = t >> 6;
  int incl = s;
  #pragma unroll
  for (int o = 1; o < 64; o <<= 1) { int y = __shfl_up(incl, o); if (l >= o) incl += y; }
  int excl = incl - s;
  __shared__ int ws[4];
  if (l == 63) ws[wid] = incl;
  __syncthreads();
  int woff = 0;
  for (int w = 0; w < wid; w++) woff += ws[w];
  int pre = bsum[b] + woff + excl;
  #pragma unroll
  for (int j = 0; j < 16; j++) { int i = base + j; if (i < n) off[i] = pre + loc[j]; }
}
__global__ void k_csr(const int* __restrict__ src, const int* __restrict__ dst,
                      const float* __restrict__ dinv, const int* __restrict__ off,
                      int* cursor, int* csr_src, float* csr_w, int e) {
  int i = blockIdx.x * 256 + threadIdx.x;
  if (i >= e) return;
  int d = dst[i], s = src[i];
  int slot = atomicAdd(&cursor[d], 1);
  int pos = off[d] + slot;
  csr_src[pos] = s;
  csr_w[pos] = dinv[s];
}

// ---------------- per-wave 3-deep-pipelined MFMA GEMM, 64x128 wave tile ----------------
// C[M,NC] = A[M,K] @ Bt[NC,K]^T.  Block = 8 independent waves (512 thr); each
// wave owns 64 rows x 128 cols (8 MFMA per 1KB A-chunk -> 2x arith intensity
// vs r14, and grid-y = NC/128 halves A re-reads).  B-slab 128 cols in LDS
// (XOR-swizzled).  Grid = (MBpad, NC/128), MBpad%8==0 -> XCD-stable m-slabs.
// EPI: 0 none | 1 +colbias | 2 +colbias,relu | 3 +rowbias[rowmap[row]*rbld+col],relu
//      4 +colbias, f32 output (C is float*, ldc in f32 elements)
template <int EPI, int K>
__global__ __launch_bounds__(512) void gemm_p(
    const u16* __restrict__ A, int lda,
    const u16* __restrict__ Bt,
    u16* __restrict__ C, int ldc,
    int M, int NC,
    const u16* __restrict__ colbias,
    const float* __restrict__ rowbias, int rbld, const int* __restrict__ rowmap) {
  __shared__ u16 Bs[128 * K];
  __shared__ u16 As[8 * 4 * 512];   // 8 waves x 4 bufs x (16 rows x 32 cols)
  const int t = threadIdx.x;
  const int m0 = blockIdx.x * 512;
  const int n0 = blockIdx.y * 128;
  if (m0 >= M) return;              // uniform: padded m-blocks exit whole
  {
    const int ng = K >> 3;
    const int tot = 128 * ng;
    for (int i = t; i < tot; i += 512) {
      int c = i / ng, g = i - c * ng;
      u16x8 v = *reinterpret_cast<const u16x8*>(Bt + (size_t)(n0 + c) * K + g * 8);
      *reinterpret_cast<u16x8*>(&Bs[c * K + (g ^ (c & 7)) * 8]) = v;
    }
  }
  __syncthreads();   // only barrier in the kernel

  const int wid = t >> 6, l = t & 63;
  const int rbase = m0 + wid * 64;
  const int lr = l & 15, lg = l >> 4;
  u16* Aw = &As[wid * 2048];
  const int srow = l >> 2;                 // 0..15: staging row
  const int sg = (l & 3) ^ (srow & 3);     // source granule for dest slot l&3

  auto stage = [&](int s) {
    int mi = s & 3, kk = s >> 2;
    int row = rbase + mi * 16 + srow;
    if (row >= M) row = M - 1;
    __builtin_amdgcn_global_load_lds(
        (const __attribute__((address_space(1))) unsigned int*)(A + (size_t)row * lda + kk * 32 + sg * 8),
        (__attribute__((address_space(3))) unsigned int*)(Aw + (s & 3) * 512), 16, 0, 0);
  };

  f32x4 acc[4][8] = {};
  bf16x8 bfr[8];
  const int S = K >> 3;   // steps: (K/32) kk-major x 4 mi-minor
  stage(0); stage(1); stage(2);
  #pragma unroll
  for (int s = 0; s < S; s++) {
    const int buf = s & 3, mi = s & 3, kk = s >> 2;
    __builtin_amdgcn_sched_barrier(0);   // fence A: stage can't hoist above step s-1
    if (s + 3 < S) stage(s + 3);
    const int rem = (s + 3 < S) ? 3 : (S - 1 - s);
    if (rem >= 3)      asm volatile("s_waitcnt vmcnt(3)" ::: "memory");
    else if (rem == 2) asm volatile("s_waitcnt vmcnt(2)" ::: "memory");
    else if (rem == 1) asm volatile("s_waitcnt vmcnt(1)" ::: "memory");
    else               asm volatile("s_waitcnt vmcnt(0)" ::: "memory");
    __builtin_amdgcn_sched_barrier(0);   // fence B: compute can't hoist above wait
    if (mi == 0) {   // B frags for this kk, reused over 4 mi steps
      #pragma unroll
      for (int ni = 0; ni < 8; ni++) {
        int g = kk * 4 + lg;
        bfr[ni] = *reinterpret_cast<const bf16x8*>(&Bs[(ni * 16 + lr) * K + (g ^ (lr & 7)) * 8]);
      }
    }
    const u16* Ab = Aw + buf * 512;
    bf16x8 af = *reinterpret_cast<const bf16x8*>(&Ab[lr * 32 + (lg ^ (lr & 3)) * 8]);
    __builtin_amdgcn_s_setprio(1);       // T5: favor MFMA-issuing wave
    #pragma unroll
    for (int ni = 0; ni < 8; ni++)
      acc[mi][ni] = __builtin_amdgcn_mfma_f32_16x16x32_bf16(af, bfr[ni], acc[mi][ni], 0, 0, 0);
    __builtin_amdgcn_s_setprio(0);
  }

  #pragma unroll
  for (int mi = 0; mi < 4; mi++) {
    int rowi[4];
    #pragma unroll
    for (int r = 0; r < 4; r++) rowi[r] = rbase + mi * 16 + lg * 4 + r;
    int rmv[4];
    if (EPI == 3) {
      #pragma unroll
      for (int r = 0; r < 4; r++) {
        int rr = rowi[r]; if (rr >= M) rr = M - 1;
        rmv[r] = rowmap[rr];
      }
    }
    #pragma unroll
    for (int ni = 0; ni < 8; ni++) {
      int col = n0 + ni * 16 + lr;
      float cbv = 0.f;
      if (EPI == 1 || EPI == 2 || EPI == 4) cbv = bf2f(colbias[col]);
      #pragma unroll
      for (int r = 0; r < 4; r++) {
        if (rowi[r] < M) {
          float v = acc[mi][ni][r];
          if (EPI == 1 || EPI == 2 || EPI == 4) v += cbv;
          if (EPI == 3) v += rowbias[(size_t)rmv[r] * rbld + col];
          if (EPI == 2 || EPI == 3) v = fmaxf(v, 0.f);
          if (EPI == 4) ((float*)(void*)C)[(size_t)rowi[r] * ldc + col] = v;
          else C[(size_t)rowi[r] * ldc + col] = f2bf(v);
        }
      }
    }
  }
}

// ---------------- fused GCN aggregate + bias + LN + ReLU + residual (+opt emit) ----------------
__global__ __launch_bounds__(256, 8) void k_agg(
    const u16* __restrict__ hw, int hwld, const u16* __restrict__ cb,
    const u16* __restrict__ lng, const u16* __restrict__ lnb,
    const u16* __restrict__ res, int resld, const float* __restrict__ dinv,
    const int* __restrict__ off, const int* __restrict__ csr_src,
    const float* __restrict__ csr_w,
    u16* __restrict__ hout, int n,
    void* __restrict__ out2, size_t obase, const int* __restrict__ flag) {
  int l = threadIdx.x & 63;
  int v = blockIdx.x * 4 + (threadIdx.x >> 6);
  if (v >= n) return;
  const int half = l >> 5;
  const int c0 = (l & 31) * 8;
  float a[8] = {0, 0, 0, 0, 0, 0, 0, 0};
  int s = off[v], e = off[v + 1];
  int i = s;
  for (; i + 7 < e; i += 8) {
    int u0 = csr_src[i + half],     u1 = csr_src[i + 2 + half];
    int u2 = csr_src[i + 4 + half], u3 = csr_src[i + 6 + half];
    float w0 = csr_w[i + half],     w1 = csr_w[i + 2 + half];
    float w2 = csr_w[i + 4 + half], w3 = csr_w[i + 6 + half];
    u16x8 r0 = *reinterpret_cast<const u16x8*>(hw + (size_t)u0 * hwld + c0);
    u16x8 r1 = *reinterpret_cast<const u16x8*>(hw + (size_t)u1 * hwld + c0);
    u16x8 r2 = *reinterpret_cast<const u16x8*>(hw + (size_t)u2 * hwld + c0);
    u16x8 r3 = *reinterpret_cast<const u16x8*>(hw + (size_t)u3 * hwld + c0);
    #pragma unroll
    for (int j = 0; j < 8; j++)
      a[j] += w0 * bf2f(r0[j]) + w1 * bf2f(r1[j]) + w2 * bf2f(r2[j]) + w3 * bf2f(r3[j]);
  }
  for (; i < e; i += 2) {
    int idx = i + half;
    if (idx < e) {
      int u = csr_src[idx];
      float w = csr_w[idx];
      u16x8 r = *reinterpret_cast<const u16x8*>(hw + (size_t)u * hwld + c0);
      #pragma unroll
      for (int j = 0; j < 8; j++) a[j] += w * bf2f(r[j]);
    }
  }
  #pragma unroll
  for (int j = 0; j < 8; j++) a[j] += __shfl_xor(a[j], 32);
  float dv = dinv[v];
  u16x8 sv = *reinterpret_cast<const u16x8*>(hw + (size_t)v * hwld + c0);
  u16x8 cbv = *reinterpret_cast<const u16x8*>(cb + c0);
  float sum = 0.f;
  #pragma unroll
  for (int j = 0; j < 8; j++) {
    a[j] = dv * (dv * bf2f(sv[j]) + a[j]) + bf2f(cbv[j]);
    sum += a[j];
  }
  #pragma unroll
  for (int o = 16; o; o >>= 1) sum += __shfl_xor(sum, o);
  float mean = sum * (1.f / 256.f);
  float vs = 0.f;
  #pragma unroll
  for (int j = 0; j < 8; j++) { float d = a[j] - mean; vs += d * d; }
  #pragma unroll
  for (int o = 16; o; o >>= 1) vs += __shfl_xor(vs, o);
  float rs = rsqrtf(vs * (1.f / 256.f) + 1e-5f);
  u16x8 gv = *reinterpret_cast<const u16x8*>(lng + c0);
  u16x8 bv = *reinterpret_cast<const u16x8*>(lnb + c0);
  u16x8 rv = *reinterpret_cast<const u16x8*>(res + (size_t)v * resld + c0);
  u16x8 ov;
  #pragma unroll
  for (int j = 0; j < 8; j++)
    ov[j] = f2bf(fmaxf((a[j] - mean) * rs * bf2f(gv[j]) + bf2f(bv[j]), 0.f) + bf2f(rv[j]));
  if (half == 0) {
    *reinterpret_cast<u16x8*>(hout + (size_t)v * 256 + c0) = ov;
    if (out2) {
      if (*flag) {
        float4 lo, hi;
        lo.x = bf2f(ov[0]); lo.y = bf2f(ov[1]); lo.z = bf2f(ov[2]); lo.w = bf2f(ov[3]);
        hi.x = bf2f(ov[4]); hi.y = bf2f(ov[5]); hi.z = bf2f(ov[6]); hi.w = bf2f(ov[7]);
        float* fo = (float*)out2 + obase + (size_t)v * 256 + c0;
        *reinterpret_cast<float4*>(fo) = lo;
        *reinterpret_cast<float4*>(fo + 4) = hi;
      } else {
        *reinterpret_cast<u16x8*>((u16*)out2 + obase + (size_t)v * 256 + c0) = ov;
      }
    }
  }
}

// ---------------- mean pool over sorted batch ----------------
__global__ __launch_bounds__(256) void k_pool(const u16* __restrict__ h, const int* __restrict__ batch,
                                              int n, float* gemb) {
  int g = blockIdx.x, c = threadIdx.x;
  int lo = 0, hi = n;
  while (lo < hi) { int mid = (lo + hi) >> 1; if (batch[mid] < g) lo = mid + 1; else hi = mid; }
  int s = lo;
  lo = s; hi = n;
  while (lo < hi) { int mid = (lo + hi) >> 1; if (batch[mid] < g + 1) lo = mid + 1; else hi = mid; }
  int e = lo;
  float a0 = 0.f, a1 = 0.f, a2 = 0.f, a3 = 0.f;
  int i = s;
  for (; i + 3 < e; i += 4) {
    a0 += bf2f(h[(size_t)i * 256 + c]);
    a1 += bf2f(h[(size_t)(i + 1) * 256 + c]);
    a2 += bf2f(h[(size_t)(i + 2) * 256 + c]);
    a3 += bf2f(h[(size_t)(i + 3) * 256 + c]);
  }
  for (; i < e; i++) a0 += bf2f(h[(size_t)i * 256 + c]);
  float acc = (a0 + a1) + (a2 + a3);
  int cnt = e - s; if (cnt < 1) cnt = 1;
  gemb[g * 256 + c] = acc / (float)cnt;
}

// ---------------- 2-layer MLP on one row per block ----------------
template <int OUTD>
__global__ __launch_bounds__(256) void k_mlp2(const float* __restrict__ inf32,
                                              const u16* __restrict__ inbf, const int* __restrict__ idx,
                                              const u16* __restrict__ W1, const u16* __restrict__ b1,
                                              const u16* __restrict__ W2, const u16* __restrict__ b2,
                                              void* __restrict__ out, size_t obase,
                                              const int* __restrict__ flag) {
  int b = blockIdx.x, t = threadIdx.x;
  __shared__ float sin_[256];
  __shared__ float sh[256];
  sin_[t] = inf32 ? inf32[b * 256 + t] : bf2f(inbf[(size_t)idx[b] * 256 + t]);
  __syncthreads();
  float acc = bf2f(b1[t]);
  #pragma unroll 8
  for (int k = 0; k < 256; k++) acc += sin_[k] * bf2f(W1[k * 256 + t]);
  sh[t] = fmaxf(acc, 0.f);
  __syncthreads();
  if (t < OUTD) {
    float a2 = bf2f(b2[t]);
    #pragma unroll 8
    for (int k = 0; k < 256; k++) a2 += sh[k] * bf2f(W2[k * OUTD + t]);
    st_out_(out, obase + (size_t)b * OUTD + t, a2, *flag);
  }
}

// ---------------- final 128->(1,5) GEMVs, one wave per row ----------------
__global__ __launch_bounds__(256) void k_final(const u16* __restrict__ t2e, const u16* __restrict__ t2b,
                                               const u16* __restrict__ w3e, const u16* __restrict__ b3e,
                                               const u16* __restrict__ w3b, const u16* __restrict__ b3b,
                                               void* __restrict__ out, size_t oe, size_t ob, int M,
                                               const int* __restrict__ flag) {
  int r = blockIdx.x * 4 + (threadIdx.x >> 6);
  int l = threadIdx.x & 63;
  if (r >= M) return;
  float p[6] = {0, 0, 0, 0, 0, 0};
  #pragma unroll
  for (int j = 0; j < 2; j++) {
    int k = l * 2 + j;
    float te = bf2f(t2e[(size_t)r * 128 + k]);
    float tb = bf2f(t2b[(size_t)r * 128 + k]);
    p[0] += te * bf2f(w3e[k]);
    #pragma unroll
    for (int q = 0; q < 5; q++) p[1 + q] += tb * bf2f(w3b[k * 5 + q]);
  }
  #pragma unroll
  for (int q = 0; q < 6; q++)
    #pragma unroll
    for (int o = 32; o; o >>= 1) p[q] += __shfl_xor(p[q], o);
  if (l == 0) {
    int f32 = *flag;
    st_out_(out, oe + r, p[0] + bf2f(b3e[0]), f32);
    #pragma unroll
    for (int q = 0; q < 5; q++)
      st_out_(out, ob + (size_t)r * 5 + q, p[1 + q] + bf2f(b3b[q]), f32);
  }
}

extern "C" void kernel_launch(void* const* d_in, const int* in_sizes, int n_in,
                              void* d_out, int out_size, void* d_ws, size_t ws_size,
                              hipStream_t stream) {
  const int N = in_sizes[0] / 128;
  const int E = in_sizes[1] / 2;
  const int B = in_sizes[3];

  const int* ei    = (const int*)d_in[1];
  const int* srcp  = ei;
  const int* dstp  = ei + E;
  const int* batch = (const int*)d_in[2];
  const int* newi  = (const int*)d_in[3];
  const int* focus = (const int*)d_in[4];

  const size_t o_stop = 0;
  const size_t o_addn = (size_t)B;
  const size_t o_addb = (size_t)B + (size_t)B * 40;
  const size_t o_emb  = o_addb + (size_t)B * 5;
  const size_t o_esel = o_emb + (size_t)N * 256;
  const size_t o_bond = o_esel + (size_t)N;

  // ---- workspace arena ----
  char* p = (char*)d_ws;
  auto alloc = [&](size_t bytes) -> void* {
    void* r = (void*)p;
    p += (bytes + 255) & ~(size_t)255;
    return r;
  };
  int* flag = (int*)alloc(4);
  static const int seg_din[NSEG] = {6,7,8,9,10,11, 12,13,14,15,16,17, 18,19,
                                    20,21,22,23, 24,25,26,27, 28,29,30,31,
                                    32,33,34,35,36,37, 38,39,40,41,42,43};
  static const int seg_len[NSEG] = {32768,256,65536,256,65536,256, 256,256,256,256,256,256,
                                    32768,256, 65536,256,256,1, 65536,256,10240,40,
                                    65536,256,1280,5, 131072,256,32768,128,128,1,
                                    131072,256,32768,128,640,5};
  int wtotal = 0;
  int seg_off[NSEG + 1];
  for (int i = 0; i < NSEG; i++) { seg_off[i] = wtotal; wtotal += seg_len[i]; }
  seg_off[NSEG] = wtotal;
  u16* wbf = (u16*)alloc((size_t)wtotal * 2);
  u16* wt_f0  = (u16*)alloc(512 * 128 * 2);   // [cw0^T ; rw0^T] fused (K=128)
  u16* wt_cw1 = (u16*)alloc(256 * 256 * 2);
  u16* wt_cw2 = (u16*)alloc(256 * 256 * 2);
  u16* wt_t1  = (u16*)alloc(512 * 256 * 2);   // [e1a^T ; b1a^T] fused
  u16* wt_e2  = (u16*)alloc(128 * 256 * 2);
  u16* wt_b2  = (u16*)alloc(128 * 256 * 2);
  u16* wt_g1  = (u16*)alloc(512 * 256 * 2);   // [e1b^T ; b1b^T] fused
  u16* cbz    = (u16*)alloc(512 * 2);         // [0 | rb0]
  u16* cbg    = (u16*)alloc(512 * 2);         // [eb1 | qb1]
  int*   deg     = (int*)alloc((size_t)N * 4);
  int*   cursor  = (int*)alloc((size_t)N * 4);
  int*   off     = (int*)alloc((size_t)(N + 1) * 4);
  float* dinv    = (float*)alloc((size_t)N * 4);
  int*   bsum    = (int*)alloc(64 * 4);
  float* gemb    = (float*)alloc((size_t)B * 256 * 4);
  float* g1full  = (float*)alloc((size_t)B * 512 * 4);
  u16*   hg      = (u16*)alloc((size_t)B * 256 * 2);   // gathered h[newi]
  int*   csr_src = (int*)alloc((size_t)E * 4);
  float* csr_w   = (float*)alloc((size_t)E * 4);
  u16*   xbf     = (u16*)alloc((size_t)N * 128 * 2);
  u16*   P1      = (u16*)alloc((size_t)N * 256 * 2);   // P1,P2 contiguous: [N][512] region
  u16*   P2      = (u16*)alloc((size_t)N * 256 * 2);
  u16*   P3      = (u16*)alloc((size_t)N * 256 * 2);

  auto wseg = [&](int i) -> u16* { return wbf + seg_off[i]; };
  u16 *cw0 = wseg(0), *cb0 = wseg(1), *cw1 = wseg(2), *cb1 = wseg(3), *cw2 = wseg(4), *cb2 = wseg(5);
  u16 *lg0 = wseg(6), *lb0 = wseg(7), *lg1 = wseg(8), *lb1 = wseg(9), *lg2 = wseg(10), *lb2 = wseg(11);
  u16 *rw0 = wseg(12), *rb0 = wseg(13);
  u16 *sw1 = wseg(14), *sb1 = wseg(15), *sw2 = wseg(16), *sb2 = wseg(17);
  u16 *aw1 = wseg(18), *ab1 = wseg(19), *aw2 = wseg(20), *ab2 = wseg(21);
  u16 *bw1 = wseg(22), *bb1 = wseg(23), *bw2 = wseg(24), *bb2 = wseg(25);
  u16 *ew1 = wseg(26), *eb1 = wseg(27), *ew2 = wseg(28), *eb2 = wseg(29), *ew3 = wseg(30), *eb3 = wseg(31);
  u16 *qw1 = wseg(32), *qb1 = wseg(33), *qw2 = wseg(34), *qb2 = wseg(35), *qw3 = wseg(36), *qb3 = wseg(37);

  // ---- dtype detect + normalize to bf16 ----
  k_detect<<<1, 64, 0, stream>>>((const u16*)d_in[0], flag);
  k_cvt_big<<<(N * 128 / 4 + 255) / 256, 256, 0, stream>>>(d_in[0], xbf, N * 128 / 4, flag);
  Cvt cd;
  for (int i = 0; i < NSEG; i++) cd.src[i] = d_in[seg_din[i]];
  for (int i = 0; i <= NSEG; i++) cd.off[i] = seg_off[i];
  k_cvt_all<<<(wtotal + 255) / 256, 256, 0, stream>>>(cd, wbf, wtotal, flag);
  k_padbias<<<2, 256, 0, stream>>>(rb0, cbz);
  k_cat2<<<2, 256, 0, stream>>>(eb1, qb1, cbg);

  const int NB = (N + 255) / 256;
  const int EBk = (E + 255) / 256;
  const int NBS = (N + SCB - 1) / SCB;

  // graph structure
  k_init<<<NB, 256, 0, stream>>>(deg, cursor, N);
  k_deg<<<EBk, 256, 0, stream>>>(dstp, deg, E);
  k_dinv<<<NB, 256, 0, stream>>>(deg, dinv, N);
  k_scanA<<<NBS, 256, 0, stream>>>(deg, bsum, N);
  k_scanB<<<1, 64, 0, stream>>>(bsum, NBS, off, N);
  k_scanC<<<NBS, 256, 0, stream>>>(deg, bsum, off, N);
  k_csr<<<EBk, 256, 0, stream>>>(srcp, dstp, dinv, off, cursor, csr_src, csr_w, E);

  // fused weight transposes (from bf16 arena)
  {
    Tr td;
    const u16* ts[NTR] = {cw0, rw0, cw1, cw2, ew1, qw1, ew2, qw2, ew1 + 65536, qw1 + 65536};
    u16* tdst[NTR] = {wt_f0, wt_f0 + 256 * 128, wt_cw1, wt_cw2, wt_t1, wt_t1 + 256 * 256,
                      wt_e2, wt_b2, wt_g1, wt_g1 + 256 * 256};
    int tlk[NTR] = {7, 7, 8, 8, 8, 8, 8, 8, 8, 8};
    int tnc[NTR] = {256, 256, 256, 256, 256, 256, 128, 128, 256, 256};
    int tlen[NTR] = {32768, 32768, 65536, 65536, 65536, 65536, 32768, 32768, 65536, 65536};
    int tot = 0;
    for (int i = 0; i < NTR; i++) {
      td.src[i] = ts[i]; td.dst[i] = tdst[i]; td.lk[i] = tlk[i]; td.nc[i] = tnc[i];
      td.off[i] = tot; tot += tlen[i];
    }
    td.off[NTR] = tot;
    k_tr_all<<<(tot + 255) / 256, 256, 0, stream>>>(td, tot);
  }

  const int MB5 = (N + 511) / 512;
  const int MBP = (MB5 + 7) & ~7;    // pad m-dim to %8==0 -> XCD-stable m-slabs
  const int AGB = (N + 3) / 4;
  u16* PF = P1;   // [N][512] region spanning P1..P2

  // fused layer0+res: PF[:,0:256]=x@cw0, PF[:,256:512]=x@rw0+rb0
  gemm_p<1, 128><<<dim3(MBP, 4), 512, 0, stream>>>(xbf, 128, wt_f0, PF, 512, N, 512, cbz, nullptr, 0, nullptr);
  k_agg<<<AGB, 256, 0, stream>>>(PF, 512, cb0, lg0, lb0, PF + 256, 512, dinv, off, csr_src, csr_w, P3, N, nullptr, 0, flag);
  // layer 1: gemm P3 -> P1; agg(P1, res=P3) -> P2
  gemm_p<0, 256><<<dim3(MBP, 2), 512, 0, stream>>>(P3, 256, wt_cw1, P1, 256, N, 256, nullptr, nullptr, 0, nullptr);
  k_agg<<<AGB, 256, 0, stream>>>(P1, 256, cb1, lg1, lb1, P3, 256, dinv, off, csr_src, csr_w, P2, N, nullptr, 0, flag);
  // layer 2: gemm P2 -> P1; agg(P1, res=P2) -> P3 + fused emit to d_out
  gemm_p<0, 256><<<dim3(MBP, 2), 512, 0, stream>>>(P2, 256, wt_cw2, P1, 256, N, 256, nullptr, nullptr, 0, nullptr);
  k_agg<<<AGB, 256, 0, stream>>>(P1, 256, cb2, lg2, lb2, P2, 256, dinv, off, csr_src, csr_w, P3, N, d_out, o_emb, flag);

  // pooling + graph-level heads
  k_pool<<<B, 256, 0, stream>>>(P3, batch, N, gemb);
  // g1full[B,512] = h[newi] @ [e1b|b1b] + [eb1|qb1]  (f32 out, via gather + MFMA GEMM)
  k_gather<<<B, 256, 0, stream>>>(P3, newi, hg, B);
  gemm_p<4, 256><<<dim3(8, 4), 512, 0, stream>>>(hg, 256, wt_g1, (u16*)(void*)g1full, 512, B, 512, cbg, nullptr, 0, nullptr);
  k_mlp2<1><<<B, 256, 0, stream>>>(gemb, nullptr, nullptr, sw1, sb1, sw2, sb2, d_out, o_stop, flag);
  k_mlp2<40><<<B, 256, 0, stream>>>(gemb, nullptr, nullptr, aw1, ab1, aw2, ab2, d_out, o_addn, flag);
  k_mlp2<5><<<B, 256, 0, stream>>>(nullptr, P3, focus, bw1, bb1, bw2, bb2, d_out, o_addb, flag);

  // fused pair-MLP layer 1: T1[N,512] = relu(emb @ [e1a|b1a] + g1full[batch])
  u16* T1 = PF;
  gemm_p<3, 256><<<dim3(MBP, 4), 512, 0, stream>>>(P3, 256, wt_t1, T1, 512, N, 512, nullptr, g1full, 512, batch);
  // pair-MLP layer 2: t2e/t2b -> P3 (free after T1 gemm)
  u16* t2e = P3;
  u16* t2b = P3 + (size_t)N * 128;
  gemm_p<2, 256><<<dim3(MBP, 1), 512, 0, stream>>>(T1, 512, wt_e2, t2e, 128, N, 128, eb2, nullptr, 0, nullptr);
  gemm_p<2, 256><<<dim3(MBP, 1), 512, 0, stream>>>(T1 + 256, 512, wt_b2, t2b, 128, N, 128, qb2, nullptr, 0, nullptr);
  k_final<<<(N + 3) / 4, 256, 0, stream>>>(t2e, t2b, ew3, eb3, qw3, qb3, d_out, o_esel, o_bond, N, flag);
}

// Round 16
// 538.589 us; speedup vs baseline: 1.1932x; 1.1932x over previous
//
#include <hip/hip_runtime.h>

typedef short bf16x8 __attribute__((ext_vector_type(8)));
typedef float f32x4 __attribute__((ext_vector_type(4)));
typedef unsigned short u16;
typedef u16 u16x4 __attribute__((ext_vector_type(4)));
typedef u16 u16x8 __attribute__((ext_vector_type(8)));

__device__ __forceinline__ float bf2f(u16 u) {
  union { float f; unsigned int i; } x; x.i = ((unsigned int)u) << 16; return x.f;
}
__device__ __forceinline__ u16 f2bf(float f) {
  union { float f; unsigned int i; } x; x.f = f;
  unsigned int r = x.i + 0x7fffu + ((x.i >> 16) & 1u);
  return (u16)(r >> 16);
}
__device__ __forceinline__ void st_out_(void* out, size_t idx, float v, int f32) {
  if (f32) ((float*)out)[idx] = v;
  else ((u16*)out)[idx] = f2bf(v);
}

// ---------------- dtype detection: fp32 vs bf16 device buffers ----------------
__global__ void k_detect(const u16* __restrict__ xx, int* flag) {
  int j = threadIdx.x;
  u16 u = xx[2 * j];
  int ex = (u >> 7) & 0xFF;
  int insane = (u != 0) && (ex < 100 || ex > 140);
  unsigned long long m = __ballot(insane);
  if (j == 0) flag[0] = (__popcll(m) > 8) ? 1 : 0;   // 1 = fp32
}

// ---------------- input normalization to bf16 (4 elems/thread) ----------------
__global__ void k_cvt_big(const void* __restrict__ src, u16* __restrict__ dst, int n4,
                          const int* __restrict__ flag) {
  int i = blockIdx.x * 256 + threadIdx.x;
  if (i >= n4) return;
  if (*flag) {
    float4 v = reinterpret_cast<const float4*>(src)[i];
    u16x4 o;
    o[0] = f2bf(v.x); o[1] = f2bf(v.y); o[2] = f2bf(v.z); o[3] = f2bf(v.w);
    reinterpret_cast<u16x4*>(dst)[i] = o;
  } else {
    reinterpret_cast<u16x4*>(dst)[i] = reinterpret_cast<const u16x4*>(src)[i];
  }
}

#define NSEG 38
struct Cvt { const void* src[NSEG]; int off[NSEG + 1]; };
__global__ void k_cvt_all(Cvt c, u16* __restrict__ dst, int total, const int* __restrict__ flag) {
  int i = blockIdx.x * 256 + threadIdx.x;
  if (i >= total) return;
  int s = 0;
  #pragma unroll 1
  while (i >= c.off[s + 1]) s++;
  int j = i - c.off[s];
  dst[i] = (*flag) ? f2bf(((const float*)c.src[s])[j]) : ((const u16*)c.src[s])[j];
}

// zero-padded colbias for fused res+layer0 GEMM: [0 x256 | rb0 x256]
__global__ void k_padbias(const u16* __restrict__ rb, u16* cbz) {
  int i = blockIdx.x * 256 + threadIdx.x;
  if (i < 512) cbz[i] = (i < 256) ? (u16)0 : rb[i - 256];
}
// concat two 256-vectors
__global__ void k_cat2(const u16* __restrict__ a, const u16* __restrict__ b, u16* dst) {
  int i = blockIdx.x * 256 + threadIdx.x;
  if (i < 512) dst[i] = (i < 256) ? a[i] : b[i - 256];
}
// gather rows: out[b] = h[idx[b]]
__global__ void k_gather(const u16* __restrict__ h, const int* __restrict__ idx,
                         u16* __restrict__ out, int rows) {
  int b = blockIdx.x, t = threadIdx.x;
  if (b < rows) out[(size_t)b * 256 + t] = h[(size_t)idx[b] * 256 + t];
}

// ---------------- fused weight transpose: dst[s][n*K+k] = src[s][k*NC+n] ----------------
#define NTR 13
struct Tr { const u16* src[NTR]; u16* dst[NTR]; int lk[NTR]; int nc[NTR]; int off[NTR + 1]; };
__global__ void k_tr_all(Tr c, int total) {
  int i = blockIdx.x * 256 + threadIdx.x;
  if (i >= total) return;
  int s = 0;
  #pragma unroll 1
  while (i >= c.off[s + 1]) s++;
  int j = i - c.off[s];
  int K = 1 << c.lk[s];
  int nrow = j >> c.lk[s], k = j & (K - 1);
  c.dst[s][j] = c.src[s][k * c.nc[s] + nrow];
}

// ---------------- graph preprocessing ----------------
__global__ void k_init(int* deg, int* cursor, int n) {
  int i = blockIdx.x * 256 + threadIdx.x;
  if (i < n) { deg[i] = 1; cursor[i] = 0; }
}
__global__ void k_deg(const int* __restrict__ dst, int* deg, int e) {
  int i = blockIdx.x * 256 + threadIdx.x;
  if (i < e) atomicAdd(&deg[dst[i]], 1);
}
__global__ void k_dinv(const int* __restrict__ deg, float* dinv, int n) {
  int i = blockIdx.x * 256 + threadIdx.x;
  if (i < n) dinv[i] = rsqrtf((float)deg[i]);
}
#define SCB 4096
__global__ __launch_bounds__(256) void k_scanA(const int* __restrict__ deg, int* bsum, int n) {
  int b = blockIdx.x, t = threadIdx.x;
  int base = b * SCB;
  int s = 0;
  for (int j = t; j < SCB; j += 256) { int i = base + j; s += (i < n) ? deg[i] - 1 : 0; }
  int l = t & 63, wid = t >> 6;
  #pragma unroll
  for (int o = 32; o; o >>= 1) s += __shfl_xor(s, o);
  __shared__ int red[4];
  if (l == 0) red[wid] = s;
  __syncthreads();
  if (t == 0) bsum[b] = red[0] + red[1] + red[2] + red[3];
}
__global__ void k_scanB(int* bsum, int nb, int* off, int n) {
  if (threadIdx.x == 0) {
    int c = 0;
    for (int i = 0; i < nb; i++) { int v = bsum[i]; bsum[i] = c; c += v; }
    off[n] = c;
  }
}
__global__ __launch_bounds__(256) void k_scanC(const int* __restrict__ deg, const int* __restrict__ bsum,
                                               int* off, int n) {
  int b = blockIdx.x, t = threadIdx.x;
  int base = b * SCB + t * 16;
  int loc[16]; int s = 0;
  #pragma unroll
  for (int j = 0; j < 16; j++) { int i = base + j; loc[j] = s; s += (i < n) ? deg[i] - 1 : 0; }
  int l = t & 63, wid = t >> 6;
  int incl = s;
  #pragma unroll
  for (int o = 1; o < 64; o <<= 1) { int y = __shfl_up(incl, o); if (l >= o) incl += y; }
  int excl = incl - s;
  __shared__ int ws[4];
  if (l == 63) ws[wid] = incl;
  __syncthreads();
  int woff = 0;
  for (int w = 0; w < wid; w++) woff += ws[w];
  int pre = bsum[b] + woff + excl;
  #pragma unroll
  for (int j = 0; j < 16; j++) { int i = base + j; if (i < n) off[i] = pre + loc[j]; }
}
__global__ void k_csr(const int* __restrict__ src, const int* __restrict__ dst,
                      const float* __restrict__ dinv, const int* __restrict__ off,
                      int* cursor, int* csr_src, float* csr_w, int e) {
  int i = blockIdx.x * 256 + threadIdx.x;
  if (i >= e) return;
  int d = dst[i], s = src[i];
  int slot = atomicAdd(&cursor[d], 1);
  int pos = off[d] + slot;
  csr_src[pos] = s;
  csr_w[pos] = dinv[s];
}

// ---------------- per-wave 3-deep-pipelined MFMA GEMM (r14 64x64 config) ----------------
// C[M,NC] = A[M,K] @ Bt[NC,K]^T.  Block = 8 independent waves (512 thr).
// Grid = (MBpad, NC/64), MBpad%8==0 -> XCD-stable m-slabs (A L2-resident).
// EPI: 0 none | 1 +colbias | 2 +colbias,relu | 3 +rowbias[rowmap[row]*rbld+col],relu
//      4 +colbias, f32 output (C is float*, ldc in f32 elements)
template <int EPI, int K>
__global__ __launch_bounds__(512) void gemm_p(
    const u16* __restrict__ A, int lda,
    const u16* __restrict__ Bt,
    u16* __restrict__ C, int ldc,
    int M, int NC,
    const u16* __restrict__ colbias,
    const float* __restrict__ rowbias, int rbld, const int* __restrict__ rowmap) {
  __shared__ u16 Bs[64 * K];
  __shared__ u16 As[8 * 4 * 512];   // 8 waves x 4 bufs x (16 rows x 32 cols)
  const int t = threadIdx.x;
  const int m0 = blockIdx.x * 512;
  const int n0 = blockIdx.y * 64;
  if (m0 >= M) return;              // uniform: padded m-blocks exit whole
  {
    const int ng = K >> 3;
    const int tot = 64 * ng;
    for (int i = t; i < tot; i += 512) {
      int c = i / ng, g = i - c * ng;
      u16x8 v = *reinterpret_cast<const u16x8*>(Bt + (size_t)(n0 + c) * K + g * 8);
      *reinterpret_cast<u16x8*>(&Bs[c * K + (g ^ (c & 7)) * 8]) = v;
    }
  }
  __syncthreads();   // only barrier in the kernel

  const int wid = t >> 6, l = t & 63;
  const int rbase = m0 + wid * 64;
  const int lr = l & 15, lg = l >> 4;
  u16* Aw = &As[wid * 2048];
  const int srow = l >> 2;                 // 0..15: staging row
  const int sg = (l & 3) ^ (srow & 3);     // source granule for dest slot l&3

  auto stage = [&](int s) {
    int mi = s & 3, kk = s >> 2;
    int row = rbase + mi * 16 + srow;
    if (row >= M) row = M - 1;
    __builtin_amdgcn_global_load_lds(
        (const __attribute__((address_space(1))) unsigned int*)(A + (size_t)row * lda + kk * 32 + sg * 8),
        (__attribute__((address_space(3))) unsigned int*)(Aw + (s & 3) * 512), 16, 0, 0);
  };

  f32x4 acc[4][4] = {};
  bf16x8 bfr[4];
  const int S = K >> 3;   // steps: (K/32) kk-major x 4 mi-minor
  stage(0); stage(1); stage(2);
  #pragma unroll
  for (int s = 0; s < S; s++) {
    const int buf = s & 3, mi = s & 3, kk = s >> 2;
    __builtin_amdgcn_sched_barrier(0);   // fence A: stage can't hoist above step s-1
    if (s + 3 < S) stage(s + 3);
    const int rem = (s + 3 < S) ? 3 : (S - 1 - s);
    if (rem >= 3)      asm volatile("s_waitcnt vmcnt(3)" ::: "memory");
    else if (rem == 2) asm volatile("s_waitcnt vmcnt(2)" ::: "memory");
    else if (rem == 1) asm volatile("s_waitcnt vmcnt(1)" ::: "memory");
    else               asm volatile("s_waitcnt vmcnt(0)" ::: "memory");
    __builtin_amdgcn_sched_barrier(0);   // fence B: compute can't hoist above wait
    if (mi == 0) {   // B frags for this kk, reused over 4 mi steps
      #pragma unroll
      for (int ni = 0; ni < 4; ni++) {
        int g = kk * 4 + lg;
        bfr[ni] = *reinterpret_cast<const bf16x8*>(&Bs[(ni * 16 + lr) * K + (g ^ (lr & 7)) * 8]);
      }
    }
    const u16* Ab = Aw + buf * 512;
    bf16x8 af = *reinterpret_cast<const bf16x8*>(&Ab[lr * 32 + (lg ^ (lr & 3)) * 8]);
    __builtin_amdgcn_s_setprio(1);       // T5: favor MFMA-issuing wave
    #pragma unroll
    for (int ni = 0; ni < 4; ni++)
      acc[mi][ni] = __builtin_amdgcn_mfma_f32_16x16x32_bf16(af, bfr[ni], acc[mi][ni], 0, 0, 0);
    __builtin_amdgcn_s_setprio(0);
  }

  #pragma unroll
  for (int mi = 0; mi < 4; mi++) {
    int rowi[4];
    #pragma unroll
    for (int r = 0; r < 4; r++) rowi[r] = rbase + mi * 16 + lg * 4 + r;
    float rbv[4][4];
    if (EPI == 3) {
      int rmv[4];
      #pragma unroll
      for (int r = 0; r < 4; r++) {
        int rr = rowi[r]; if (rr >= M) rr = M - 1;
        rmv[r] = rowmap[rr];
      }
      #pragma unroll
      for (int ni = 0; ni < 4; ni++)
        #pragma unroll
        for (int r = 0; r < 4; r++)
          rbv[ni][r] = rowbias[(size_t)rmv[r] * rbld + n0 + ni * 16 + lr];
    }
    #pragma unroll
    for (int ni = 0; ni < 4; ni++) {
      int col = n0 + ni * 16 + lr;
      float cbv = 0.f;
      if (EPI == 1 || EPI == 2 || EPI == 4) cbv = bf2f(colbias[col]);
      #pragma unroll
      for (int r = 0; r < 4; r++) {
        if (rowi[r] < M) {
          float v = acc[mi][ni][r];
          if (EPI == 1 || EPI == 2 || EPI == 4) v += cbv;
          if (EPI == 3) v += rbv[ni][r];
          if (EPI == 2 || EPI == 3) v = fmaxf(v, 0.f);
          if (EPI == 4) ((float*)(void*)C)[(size_t)rowi[r] * ldc + col] = v;
          else C[(size_t)rowi[r] * ldc + col] = f2bf(v);
        }
      }
    }
  }
}

// ---------------- fused GCN aggregate + bias + LN + ReLU + residual (+opt emit) ----------------
__global__ __launch_bounds__(256, 8) void k_agg(
    const u16* __restrict__ hw, int hwld, const u16* __restrict__ cb,
    const u16* __restrict__ lng, const u16* __restrict__ lnb,
    const u16* __restrict__ res, int resld, const float* __restrict__ dinv,
    const int* __restrict__ off, const int* __restrict__ csr_src,
    const float* __restrict__ csr_w,
    u16* __restrict__ hout, int n,
    void* __restrict__ out2, size_t obase, const int* __restrict__ flag) {
  int l = threadIdx.x & 63;
  int v = blockIdx.x * 4 + (threadIdx.x >> 6);
  if (v >= n) return;
  const int half = l >> 5;
  const int c0 = (l & 31) * 8;
  float a[8] = {0, 0, 0, 0, 0, 0, 0, 0};
  int s = off[v], e = off[v + 1];
  int i = s;
  for (; i + 7 < e; i += 8) {
    int u0 = csr_src[i + half],     u1 = csr_src[i + 2 + half];
    int u2 = csr_src[i + 4 + half], u3 = csr_src[i + 6 + half];
    float w0 = csr_w[i + half],     w1 = csr_w[i + 2 + half];
    float w2 = csr_w[i + 4 + half], w3 = csr_w[i + 6 + half];
    u16x8 r0 = *reinterpret_cast<const u16x8*>(hw + (size_t)u0 * hwld + c0);
    u16x8 r1 = *reinterpret_cast<const u16x8*>(hw + (size_t)u1 * hwld + c0);
    u16x8 r2 = *reinterpret_cast<const u16x8*>(hw + (size_t)u2 * hwld + c0);
    u16x8 r3 = *reinterpret_cast<const u16x8*>(hw + (size_t)u3 * hwld + c0);
    #pragma unroll
    for (int j = 0; j < 8; j++)
      a[j] += w0 * bf2f(r0[j]) + w1 * bf2f(r1[j]) + w2 * bf2f(r2[j]) + w3 * bf2f(r3[j]);
  }
  for (; i < e; i += 2) {
    int idx = i + half;
    if (idx < e) {
      int u = csr_src[idx];
      float w = csr_w[idx];
      u16x8 r = *reinterpret_cast<const u16x8*>(hw + (size_t)u * hwld + c0);
      #pragma unroll
      for (int j = 0; j < 8; j++) a[j] += w * bf2f(r[j]);
    }
  }
  #pragma unroll
  for (int j = 0; j < 8; j++) a[j] += __shfl_xor(a[j], 32);
  float dv = dinv[v];
  u16x8 sv = *reinterpret_cast<const u16x8*>(hw + (size_t)v * hwld + c0);
  u16x8 cbv = *reinterpret_cast<const u16x8*>(cb + c0);
  float sum = 0.f;
  #pragma unroll
  for (int j = 0; j < 8; j++) {
    a[j] = dv * (dv * bf2f(sv[j]) + a[j]) + bf2f(cbv[j]);
    sum += a[j];
  }
  #pragma unroll
  for (int o = 16; o; o >>= 1) sum += __shfl_xor(sum, o);
  float mean = sum * (1.f / 256.f);
  float vs = 0.f;
  #pragma unroll
  for (int j = 0; j < 8; j++) { float d = a[j] - mean; vs += d * d; }
  #pragma unroll
  for (int o = 16; o; o >>= 1) vs += __shfl_xor(vs, o);
  float rs = rsqrtf(vs * (1.f / 256.f) + 1e-5f);
  u16x8 gv = *reinterpret_cast<const u16x8*>(lng + c0);
  u16x8 bv = *reinterpret_cast<const u16x8*>(lnb + c0);
  u16x8 rv = *reinterpret_cast<const u16x8*>(res + (size_t)v * resld + c0);
  u16x8 ov;
  #pragma unroll
  for (int j = 0; j < 8; j++)
    ov[j] = f2bf(fmaxf((a[j] - mean) * rs * bf2f(gv[j]) + bf2f(bv[j]), 0.f) + bf2f(rv[j]));
  if (half == 0) {
    *reinterpret_cast<u16x8*>(hout + (size_t)v * 256 + c0) = ov;
    if (out2) {
      if (*flag) {
        float4 lo, hi;
        lo.x = bf2f(ov[0]); lo.y = bf2f(ov[1]); lo.z = bf2f(ov[2]); lo.w = bf2f(ov[3]);
        hi.x = bf2f(ov[4]); hi.y = bf2f(ov[5]); hi.z = bf2f(ov[6]); hi.w = bf2f(ov[7]);
        float* fo = (float*)out2 + obase + (size_t)v * 256 + c0;
        *reinterpret_cast<float4*>(fo) = lo;
        *reinterpret_cast<float4*>(fo + 4) = hi;
      } else {
        *reinterpret_cast<u16x8*>((u16*)out2 + obase + (size_t)v * 256 + c0) = ov;
      }
    }
  }
}

// ---------------- mean pool over sorted batch -> bf16 ----------------
__global__ __launch_bounds__(256) void k_pool(const u16* __restrict__ h, const int* __restrict__ batch,
                                              int n, u16* gembbf) {
  int g = blockIdx.x, c = threadIdx.x;
  int lo = 0, hi = n;
  while (lo < hi) { int mid = (lo + hi) >> 1; if (batch[mid] < g) lo = mid + 1; else hi = mid; }
  int s = lo;
  lo = s; hi = n;
  while (lo < hi) { int mid = (lo + hi) >> 1; if (batch[mid] < g + 1) lo = mid + 1; else hi = mid; }
  int e = lo;
  float a0 = 0.f, a1 = 0.f, a2 = 0.f, a3 = 0.f;
  int i = s;
  for (; i + 3 < e; i += 4) {
    a0 += bf2f(h[(size_t)i * 256 + c]);
    a1 += bf2f(h[(size_t)(i + 1) * 256 + c]);
    a2 += bf2f(h[(size_t)(i + 2) * 256 + c]);
    a3 += bf2f(h[(size_t)(i + 3) * 256 + c]);
  }
  for (; i < e; i++) a0 += bf2f(h[(size_t)i * 256 + c]);
  float acc = (a0 + a1) + (a2 + a3);
  int cnt = e - s; if (cnt < 1) cnt = 1;
  gembbf[(size_t)g * 256 + c] = f2bf(acc / (float)cnt);
}

// ---------------- head second layers: stop(1)+addn(40)+bond(5) per graph row ----------------
__global__ __launch_bounds__(256) void k_heads2(
    const u16* __restrict__ Hsa, const u16* __restrict__ H1b,
    const u16* __restrict__ sw2, const u16* __restrict__ sb2,
    const u16* __restrict__ aw2, const u16* __restrict__ ab2,
    const u16* __restrict__ bw2, const u16* __restrict__ bb2,
    void* __restrict__ out, size_t o_stop, size_t o_addn, size_t o_addb,
    const int* __restrict__ flag) {
  int b = blockIdx.x, t = threadIdx.x;
  __shared__ float s1[512];
  __shared__ float s2[256];
  s1[t] = bf2f(Hsa[(size_t)b * 512 + t]);
  s1[t + 256] = bf2f(Hsa[(size_t)b * 512 + t + 256]);
  s2[t] = bf2f(H1b[(size_t)b * 256 + t]);
  __syncthreads();
  int f32 = *flag;
  if (t == 0) {
    float a = bf2f(sb2[0]);
    #pragma unroll 8
    for (int k = 0; k < 256; k++) a += s1[k] * bf2f(sw2[k]);
    st_out_(out, o_stop + b, a, f32);
  } else if (t < 41) {
    int j = t - 1;
    float a = bf2f(ab2[j]);
    #pragma unroll 8
    for (int k = 0; k < 256; k++) a += s1[256 + k] * bf2f(aw2[k * 40 + j]);
    st_out_(out, o_addn + (size_t)b * 40 + j, a, f32);
  } else if (t < 46) {
    int q = t - 41;
    float a = bf2f(bb2[q]);
    #pragma unroll 8
    for (int k = 0; k < 256; k++) a += s2[k] * bf2f(bw2[k * 5 + q]);
    st_out_(out, o_addb + (size_t)b * 5 + q, a, f32);
  }
}

// ---------------- final 128->(1,5) GEMVs, one wave per row ----------------
__global__ __launch_bounds__(256) void k_final(const u16* __restrict__ t2e, const u16* __restrict__ t2b,
                                               const u16* __restrict__ w3e, const u16* __restrict__ b3e,
                                               const u16* __restrict__ w3b, const u16* __restrict__ b3b,
                                               void* __restrict__ out, size_t oe, size_t ob, int M,
                                               const int* __restrict__ flag) {
  int r = blockIdx.x * 4 + (threadIdx.x >> 6);
  int l = threadIdx.x & 63;
  if (r >= M) return;
  float p[6] = {0, 0, 0, 0, 0, 0};
  #pragma unroll
  for (int j = 0; j < 2; j++) {
    int k = l * 2 + j;
    float te = bf2f(t2e[(size_t)r * 128 + k]);
    float tb = bf2f(t2b[(size_t)r * 128 + k]);
    p[0] += te * bf2f(w3e[k]);
    #pragma unroll
    for (int q = 0; q < 5; q++) p[1 + q] += tb * bf2f(w3b[k * 5 + q]);
  }
  #pragma unroll
  for (int q = 0; q < 6; q++)
    #pragma unroll
    for (int o = 32; o; o >>= 1) p[q] += __shfl_xor(p[q], o);
  if (l == 0) {
    int f32 = *flag;
    st_out_(out, oe + r, p[0] + bf2f(b3e[0]), f32);
    #pragma unroll
    for (int q = 0; q < 5; q++)
      st_out_(out, ob + (size_t)r * 5 + q, p[1 + q] + bf2f(b3b[q]), f32);
  }
}

extern "C" void kernel_launch(void* const* d_in, const int* in_sizes, int n_in,
                              void* d_out, int out_size, void* d_ws, size_t ws_size,
                              hipStream_t stream) {
  const int N = in_sizes[0] / 128;
  const int E = in_sizes[1] / 2;
  const int B = in_sizes[3];

  const int* ei    = (const int*)d_in[1];
  const int* srcp  = ei;
  const int* dstp  = ei + E;
  const int* batch = (const int*)d_in[2];
  const int* newi  = (const int*)d_in[3];
  const int* focus = (const int*)d_in[4];

  const size_t o_stop = 0;
  const size_t o_addn = (size_t)B;
  const size_t o_addb = (size_t)B + (size_t)B * 40;
  const size_t o_emb  = o_addb + (size_t)B * 5;
  const size_t o_esel = o_emb + (size_t)N * 256;
  const size_t o_bond = o_esel + (size_t)N;

  // ---- workspace arena ----
  char* p = (char*)d_ws;
  auto alloc = [&](size_t bytes) -> void* {
    void* r = (void*)p;
    p += (bytes + 255) & ~(size_t)255;
    return r;
  };
  int* flag = (int*)alloc(4);
  static const int seg_din[NSEG] = {6,7,8,9,10,11, 12,13,14,15,16,17, 18,19,
                                    20,21,22,23, 24,25,26,27, 28,29,30,31,
                                    32,33,34,35,36,37, 38,39,40,41,42,43};
  static const int seg_len[NSEG] = {32768,256,65536,256,65536,256, 256,256,256,256,256,256,
                                    32768,256, 65536,256,256,1, 65536,256,10240,40,
                                    65536,256,1280,5, 131072,256,32768,128,128,1,
                                    131072,256,32768,128,640,5};
  int wtotal = 0;
  int seg_off[NSEG + 1];
  for (int i = 0; i < NSEG; i++) { seg_off[i] = wtotal; wtotal += seg_len[i]; }
  seg_off[NSEG] = wtotal;
  u16* wbf = (u16*)alloc((size_t)wtotal * 2);
  u16* wt_f0  = (u16*)alloc(512 * 128 * 2);   // [cw0^T ; rw0^T] fused (K=128)
  u16* wt_cw1 = (u16*)alloc(256 * 256 * 2);
  u16* wt_cw2 = (u16*)alloc(256 * 256 * 2);
  u16* wt_t1  = (u16*)alloc(512 * 256 * 2);   // [e1a^T ; b1a^T] fused
  u16* wt_e2  = (u16*)alloc(128 * 256 * 2);
  u16* wt_b2  = (u16*)alloc(128 * 256 * 2);
  u16* wt_g1  = (u16*)alloc(512 * 256 * 2);   // [e1b^T ; b1b^T] fused
  u16* wt_sa  = (u16*)alloc(512 * 256 * 2);   // [sw1^T ; aw1^T] fused
  u16* wt_b1h = (u16*)alloc(256 * 256 * 2);   // bw1^T
  u16* cbz    = (u16*)alloc(512 * 2);         // [0 | rb0]
  u16* cbg    = (u16*)alloc(512 * 2);         // [eb1 | qb1]
  u16* cbsa   = (u16*)alloc(512 * 2);         // [sb1 | ab1]
  int*   deg     = (int*)alloc((size_t)N * 4);
  int*   cursor  = (int*)alloc((size_t)N * 4);
  int*   off     = (int*)alloc((size_t)(N + 1) * 4);
  float* dinv    = (float*)alloc((size_t)N * 4);
  int*   bsum    = (int*)alloc(64 * 4);
  u16*   gembbf  = (u16*)alloc((size_t)B * 256 * 2);
  float* g1full  = (float*)alloc((size_t)B * 512 * 4);
  u16*   hg      = (u16*)alloc((size_t)B * 256 * 2);   // gathered h[newi]
  u16*   hgf     = (u16*)alloc((size_t)B * 256 * 2);   // gathered h[focus]
  u16*   Hsa     = (u16*)alloc((size_t)B * 512 * 2);   // stop/addn hidden
  u16*   H1b     = (u16*)alloc((size_t)B * 256 * 2);   // bond hidden
  int*   csr_src = (int*)alloc((size_t)E * 4);
  float* csr_w   = (float*)alloc((size_t)E * 4);
  u16*   xbf     = (u16*)alloc((size_t)N * 128 * 2);
  u16*   P1      = (u16*)alloc((size_t)N * 256 * 2);   // P1,P2 contiguous: [N][512] region
  u16*   P2      = (u16*)alloc((size_t)N * 256 * 2);
  u16*   P3      = (u16*)alloc((size_t)N * 256 * 2);

  auto wseg = [&](int i) -> u16* { return wbf + seg_off[i]; };
  u16 *cw0 = wseg(0), *cb0 = wseg(1), *cw1 = wseg(2), *cb1 = wseg(3), *cw2 = wseg(4), *cb2 = wseg(5);
  u16 *lg0 = wseg(6), *lb0 = wseg(7), *lg1 = wseg(8), *lb1 = wseg(9), *lg2 = wseg(10), *lb2 = wseg(11);
  u16 *rw0 = wseg(12), *rb0 = wseg(13);
  u16 *sw1 = wseg(14), *sb1 = wseg(15), *sw2 = wseg(16), *sb2 = wseg(17);
  u16 *aw1 = wseg(18), *ab1 = wseg(19), *aw2 = wseg(20), *ab2 = wseg(21);
  u16 *bw1 = wseg(22), *bb1 = wseg(23), *bw2 = wseg(24), *bb2 = wseg(25);
  u16 *ew1 = wseg(26), *eb1 = wseg(27), *ew2 = wseg(28), *eb2 = wseg(29), *ew3 = wseg(30), *eb3 = wseg(31);
  u16 *qw1 = wseg(32), *qb1 = wseg(33), *qw2 = wseg(34), *qb2 = wseg(35), *qw3 = wseg(36), *qb3 = wseg(37);

  // ---- dtype detect + normalize to bf16 ----
  k_detect<<<1, 64, 0, stream>>>((const u16*)d_in[0], flag);
  k_cvt_big<<<(N * 128 / 4 + 255) / 256, 256, 0, stream>>>(d_in[0], xbf, N * 128 / 4, flag);
  Cvt cd;
  for (int i = 0; i < NSEG; i++) cd.src[i] = d_in[seg_din[i]];
  for (int i = 0; i <= NSEG; i++) cd.off[i] = seg_off[i];
  k_cvt_all<<<(wtotal + 255) / 256, 256, 0, stream>>>(cd, wbf, wtotal, flag);
  k_padbias<<<2, 256, 0, stream>>>(rb0, cbz);
  k_cat2<<<2, 256, 0, stream>>>(eb1, qb1, cbg);
  k_cat2<<<2, 256, 0, stream>>>(sb1, ab1, cbsa);

  const int NB = (N + 255) / 256;
  const int EBk = (E + 255) / 256;
  const int NBS = (N + SCB - 1) / SCB;

  // graph structure
  k_init<<<NB, 256, 0, stream>>>(deg, cursor, N);
  k_deg<<<EBk, 256, 0, stream>>>(dstp, deg, E);
  k_dinv<<<NB, 256, 0, stream>>>(deg, dinv, N);
  k_scanA<<<NBS, 256, 0, stream>>>(deg, bsum, N);
  k_scanB<<<1, 64, 0, stream>>>(bsum, NBS, off, N);
  k_scanC<<<NBS, 256, 0, stream>>>(deg, bsum, off, N);
  k_csr<<<EBk, 256, 0, stream>>>(srcp, dstp, dinv, off, cursor, csr_src, csr_w, E);

  // fused weight transposes (from bf16 arena)
  {
    Tr td;
    const u16* ts[NTR] = {cw0, rw0, cw1, cw2, ew1, qw1, ew2, qw2, ew1 + 65536, qw1 + 65536,
                          sw1, aw1, bw1};
    u16* tdst[NTR] = {wt_f0, wt_f0 + 256 * 128, wt_cw1, wt_cw2, wt_t1, wt_t1 + 256 * 256,
                      wt_e2, wt_b2, wt_g1, wt_g1 + 256 * 256,
                      wt_sa, wt_sa + 256 * 256, wt_b1h};
    int tlk[NTR] = {7, 7, 8, 8, 8, 8, 8, 8, 8, 8, 8, 8, 8};
    int tnc[NTR] = {256, 256, 256, 256, 256, 256, 128, 128, 256, 256, 256, 256, 256};
    int tlen[NTR] = {32768, 32768, 65536, 65536, 65536, 65536, 32768, 32768, 65536, 65536,
                     65536, 65536, 65536};
    int tot = 0;
    for (int i = 0; i < NTR; i++) {
      td.src[i] = ts[i]; td.dst[i] = tdst[i]; td.lk[i] = tlk[i]; td.nc[i] = tnc[i];
      td.off[i] = tot; tot += tlen[i];
    }
    td.off[NTR] = tot;
    k_tr_all<<<(tot + 255) / 256, 256, 0, stream>>>(td, tot);
  }

  const int MB5 = (N + 511) / 512;
  const int MBP = (MB5 + 7) & ~7;    // pad m-dim to %8==0 -> XCD-stable m-slabs
  const int AGB = (N + 3) / 4;
  u16* PF = P1;   // [N][512] region spanning P1..P2

  // fused layer0+res: PF[:,0:256]=x@cw0, PF[:,256:512]=x@rw0+rb0
  gemm_p<1, 128><<<dim3(MBP, 8), 512, 0, stream>>>(xbf, 128, wt_f0, PF, 512, N, 512, cbz, nullptr, 0, nullptr);
  k_agg<<<AGB, 256, 0, stream>>>(PF, 512, cb0, lg0, lb0, PF + 256, 512, dinv, off, csr_src, csr_w, P3, N, nullptr, 0, flag);
  // layer 1: gemm P3 -> P1; agg(P1, res=P3) -> P2
  gemm_p<0, 256><<<dim3(MBP, 4), 512, 0, stream>>>(P3, 256, wt_cw1, P1, 256, N, 256, nullptr, nullptr, 0, nullptr);
  k_agg<<<AGB, 256, 0, stream>>>(P1, 256, cb1, lg1, lb1, P3, 256, dinv, off, csr_src, csr_w, P2, N, nullptr, 0, flag);
  // layer 2: gemm P2 -> P1; agg(P1, res=P2) -> P3 + fused emit to d_out
  gemm_p<0, 256><<<dim3(MBP, 4), 512, 0, stream>>>(P2, 256, wt_cw2, P1, 256, N, 256, nullptr, nullptr, 0, nullptr);
  k_agg<<<AGB, 256, 0, stream>>>(P1, 256, cb2, lg2, lb2, P2, 256, dinv, off, csr_src, csr_w, P3, N, d_out, o_emb, flag);

  // pooling + graph-level heads (all hidden layers via MFMA GEMM)
  k_pool<<<B, 256, 0, stream>>>(P3, batch, N, gembbf);
  k_gather<<<B, 256, 0, stream>>>(P3, newi, hg, B);
  k_gather<<<B, 256, 0, stream>>>(P3, focus, hgf, B);
  // g1full[B,512] = h[newi] @ [e1b|b1b] + [eb1|qb1]  (f32 out)
  gemm_p<4, 256><<<dim3(8, 8), 512, 0, stream>>>(hg, 256, wt_g1, (u16*)(void*)g1full, 512, B, 512, cbg, nullptr, 0, nullptr);
  // Hsa[B,512] = relu(gemb @ [sw1|aw1] + [sb1|ab1]);  H1b[B,256] = relu(h[focus] @ bw1 + bb1)
  gemm_p<2, 256><<<dim3(8, 8), 512, 0, stream>>>(gembbf, 256, wt_sa, Hsa, 512, B, 512, cbsa, nullptr, 0, nullptr);
  gemm_p<2, 256><<<dim3(8, 4), 512, 0, stream>>>(hgf, 256, wt_b1h, H1b, 256, B, 256, bb1, nullptr, 0, nullptr);
  k_heads2<<<B, 256, 0, stream>>>(Hsa, H1b, sw2, sb2, aw2, ab2, bw2, bb2,
                                  d_out, o_stop, o_addn, o_addb, flag);

  // fused pair-MLP layer 1: T1[N,512] = relu(emb @ [e1a|b1a] + g1full[batch])
  u16* T1 = PF;
  gemm_p<3, 256><<<dim3(MBP, 8), 512, 0, stream>>>(P3, 256, wt_t1, T1, 512, N, 512, nullptr, g1full, 512, batch);
  // pair-MLP layer 2: t2e/t2b -> P3 (free after T1 gemm)
  u16* t2e = P3;
  u16* t2b = P3 + (size_t)N * 128;
  gemm_p<2, 256><<<dim3(MBP, 2), 512, 0, stream>>>(T1, 512, wt_e2, t2e, 128, N, 128, eb2, nullptr, 0, nullptr);
  gemm_p<2, 256><<<dim3(MBP, 2), 512, 0, stream>>>(T1 + 256, 512, wt_b2, t2b, 128, N, 128, qb2, nullptr, 0, nullptr);
  k_final<<<(N + 3) / 4, 256, 0, stream>>>(t2e, t2b, ew3, eb3, qw3, qb3, d_out, o_esel, o_bond, N, flag);
}